// Round 2
// baseline (138.977 us; speedup 1.0000x reference)
//
#include <hip/hip_runtime.h>
#include <math.h>

#define D_FEAT 128
#define D_DOT 4

// One node per lane: pn[v][k] = sum_d n[v][d] * W[k][d]  (raw projection).
// W (2KB) staged in LDS, read as broadcast (conflict-free). 32 independent
// float4 loads per lane -> high memory-level parallelism, no cross-lane ops.
__global__ __launch_bounds__(256) void node_proj_kernel(
    const float* __restrict__ n,
    const float* __restrict__ W,
    float* __restrict__ pn,
    int n_nodes)
{
    __shared__ float4 Wl[D_DOT][32];
    if (threadIdx.x < 128) {
        Wl[threadIdx.x >> 5][threadIdx.x & 31] =
            reinterpret_cast<const float4*>(W)[threadIdx.x];
    }
    __syncthreads();

    const int stride = gridDim.x * blockDim.x;
    for (int row = blockIdx.x * blockDim.x + threadIdx.x; row < n_nodes; row += stride) {
        const float4* r = reinterpret_cast<const float4*>(n + (size_t)row * D_FEAT);
        float a0 = 0.f, a1 = 0.f, a2 = 0.f, a3 = 0.f;
#pragma unroll 8
        for (int c = 0; c < 32; ++c) {
            const float4 x  = r[c];
            const float4 w0 = Wl[0][c], w1 = Wl[1][c], w2 = Wl[2][c], w3 = Wl[3][c];
            a0 += x.x * w0.x + x.y * w0.y + x.z * w0.z + x.w * w0.w;
            a1 += x.x * w1.x + x.y * w1.y + x.z * w1.z + x.w * w1.w;
            a2 += x.x * w2.x + x.y * w2.y + x.z * w2.z + x.w * w2.w;
            a3 += x.x * w3.x + x.y * w3.y + x.z * w3.z + x.w * w3.w;
        }
        *reinterpret_cast<float4*>(&pn[(size_t)row * D_DOT]) = make_float4(a0, a1, a2, a3);
    }
}

// Two edges per lane (amortizes the LDS W reads). Per edge:
//   pe = W·e[edge];  hs = .5*(pn[src]+pe)+b;  hd = .5*(pn[dst]+pe)+b;
//   out = sigmoid(hs·hd)
__global__ __launch_bounds__(256) void edge_score_kernel(
    const float* __restrict__ e,
    const float* __restrict__ W,
    const float* __restrict__ bias,
    const float* __restrict__ pn,
    const int* __restrict__ src_idx,
    const int* __restrict__ dst_idx,
    float* __restrict__ out,
    int n_edges)
{
    __shared__ float4 Wl[D_DOT][32];
    if (threadIdx.x < 128) {
        Wl[threadIdx.x >> 5][threadIdx.x & 31] =
            reinterpret_cast<const float4*>(W)[threadIdx.x];
    }
    __syncthreads();

    const float b0 = bias[0], b1 = bias[1], b2 = bias[2], b3 = bias[3];
    const int stride2 = (gridDim.x * blockDim.x) * 2;
    const int tid = blockIdx.x * blockDim.x + threadIdx.x;

    for (int base = tid * 2; base < n_edges; base += stride2) {
        // n_edges is even in this problem; base+1 < n_edges whenever base < n_edges.
        const float4* r0 = reinterpret_cast<const float4*>(e + (size_t)base * D_FEAT);
        const float4* r1 = r0 + 32;
        float a00 = 0.f, a01 = 0.f, a02 = 0.f, a03 = 0.f;
        float a10 = 0.f, a11 = 0.f, a12 = 0.f, a13 = 0.f;
#pragma unroll 4
        for (int c = 0; c < 32; ++c) {
            const float4 x0 = r0[c];
            const float4 x1 = r1[c];
            const float4 w0 = Wl[0][c], w1 = Wl[1][c], w2 = Wl[2][c], w3 = Wl[3][c];
            a00 += x0.x * w0.x + x0.y * w0.y + x0.z * w0.z + x0.w * w0.w;
            a01 += x0.x * w1.x + x0.y * w1.y + x0.z * w1.z + x0.w * w1.w;
            a02 += x0.x * w2.x + x0.y * w2.y + x0.z * w2.z + x0.w * w2.w;
            a03 += x0.x * w3.x + x0.y * w3.y + x0.z * w3.z + x0.w * w3.w;
            a10 += x1.x * w0.x + x1.y * w0.y + x1.z * w0.z + x1.w * w0.w;
            a11 += x1.x * w1.x + x1.y * w1.y + x1.z * w1.z + x1.w * w1.w;
            a12 += x1.x * w2.x + x1.y * w2.y + x1.z * w2.z + x1.w * w2.w;
            a13 += x1.x * w3.x + x1.y * w3.y + x1.z * w3.z + x1.w * w3.w;
        }
        const int2 s01 = *reinterpret_cast<const int2*>(&src_idx[base]);
        const int2 d01 = *reinterpret_cast<const int2*>(&dst_idx[base]);
        {
            const float4 ps = *reinterpret_cast<const float4*>(&pn[(size_t)s01.x * D_DOT]);
            const float4 pd = *reinterpret_cast<const float4*>(&pn[(size_t)d01.x * D_DOT]);
            float hs, hd, dot = 0.f;
            hs = 0.5f * (ps.x + a00) + b0; hd = 0.5f * (pd.x + a00) + b0; dot += hs * hd;
            hs = 0.5f * (ps.y + a01) + b1; hd = 0.5f * (pd.y + a01) + b1; dot += hs * hd;
            hs = 0.5f * (ps.z + a02) + b2; hd = 0.5f * (pd.z + a02) + b2; dot += hs * hd;
            hs = 0.5f * (ps.w + a03) + b3; hd = 0.5f * (pd.w + a03) + b3; dot += hs * hd;
            out[base] = 1.0f / (1.0f + __expf(-dot));
        }
        {
            const float4 ps = *reinterpret_cast<const float4*>(&pn[(size_t)s01.y * D_DOT]);
            const float4 pd = *reinterpret_cast<const float4*>(&pn[(size_t)d01.y * D_DOT]);
            float hs, hd, dot = 0.f;
            hs = 0.5f * (ps.x + a10) + b0; hd = 0.5f * (pd.x + a10) + b0; dot += hs * hd;
            hs = 0.5f * (ps.y + a11) + b1; hd = 0.5f * (pd.y + a11) + b1; dot += hs * hd;
            hs = 0.5f * (ps.z + a12) + b2; hd = 0.5f * (pd.z + a12) + b2; dot += hs * hd;
            hs = 0.5f * (ps.w + a13) + b3; hd = 0.5f * (pd.w + a13) + b3; dot += hs * hd;
            out[base + 1] = 1.0f / (1.0f + __expf(-dot));
        }
    }
}

extern "C" void kernel_launch(void* const* d_in, const int* in_sizes, int n_in,
                              void* d_out, int out_size, void* d_ws, size_t ws_size,
                              hipStream_t stream) {
    const float* n    = (const float*)d_in[0];
    const float* e    = (const float*)d_in[1];
    const float* W    = (const float*)d_in[2];
    const float* bias = (const float*)d_in[3];
    const int*   src  = (const int*)d_in[4];
    const int*   dst  = (const int*)d_in[5];
    float* out = (float*)d_out;

    const int n_nodes = in_sizes[0] / D_FEAT;
    const int n_edges = in_sizes[1] / D_FEAT;

    float* pn = (float*)d_ws;  // n_nodes * 4 floats = 1.6 MB scratch

    const int nblk = (n_nodes + 255) / 256;                 // 1 node / lane
    const int eblk = (n_edges + 511) / 512;                 // 2 edges / lane
    node_proj_kernel<<<nblk, 256, 0, stream>>>(n, W, pn, n_nodes);
    edge_score_kernel<<<eblk, 256, 0, stream>>>(e, W, bias, pn, src, dst, out, n_edges);
}